// Round 1
// baseline (174.171 us; speedup 1.0000x reference)
//
#include <hip/hip_runtime.h>
#include <math.h>

#define BATCH 8
#define NTOK  4096
#define DIM   64
#define BM    128
#define NT    (NTOK / BM)            // 32 tiles per dim
#define TPB   (NT * (NT + 1) / 2)    // 528 upper-tri tile pairs per batch
#define KAPPA 0.5f

// One block per (batch, upper-tri 128x128 tile pair). Computes the tile of the
// Gram matrix via LDS-staged fp32 outer-product accumulation, then a block-local
// (max, sum-exp) with weights {0,1,2} exploiting symmetry. Writes (M, S) to ws.
__global__ __launch_bounds__(256, 2)
void gram_lse_partial(const float* __restrict__ emb, float* __restrict__ ws) {
    // Transposed staging: As[k*BM + (row ^ 8*((k>>2)&3))]
    __shared__ float As[DIM * BM];
    __shared__ float Bs[DIM * BM];

    const int tid = threadIdx.x;
    const int bb  = blockIdx.x;
    const int b   = bb / TPB;
    int t = bb - b * TPB;
    int ti = 0;
    while (t >= NT - ti) { t -= NT - ti; ++ti; }
    const int tj = ti + t;

    const float* embA = emb + ((size_t)b * NTOK + (size_t)ti * BM) * DIM;
    const float* embB = emb + ((size_t)b * NTOK + (size_t)tj * BM) * DIM;

    // ---- global -> LDS (transpose with XOR swizzle) ----
    {
        const int c  = tid & 15;   // float4 group: k = 4c..4c+3
        const int rb = tid >> 4;   // 0..15
        const int m8 = 8 * (c & 3);
#pragma unroll
        for (int r = 0; r < 8; ++r) {
            const int row = rb + 16 * r;
            const float4 ga = *(const float4*)(embA + (size_t)row * DIM + c * 4);
            const float4 gb = *(const float4*)(embB + (size_t)row * DIM + c * 4);
            const int srow = row ^ m8;
            As[(4 * c + 0) * BM + srow] = ga.x;
            As[(4 * c + 1) * BM + srow] = ga.y;
            As[(4 * c + 2) * BM + srow] = ga.z;
            As[(4 * c + 3) * BM + srow] = ga.w;
            Bs[(4 * c + 0) * BM + srow] = gb.x;
            Bs[(4 * c + 1) * BM + srow] = gb.y;
            Bs[(4 * c + 2) * BM + srow] = gb.z;
            Bs[(4 * c + 3) * BM + srow] = gb.w;
        }
    }
    __syncthreads();

    // ---- 8x8 microtile accumulation ----
    const int tx = tid & 15;
    const int ty = tid >> 4;
    float acc[8][8];
#pragma unroll
    for (int i = 0; i < 8; ++i)
#pragma unroll
        for (int j = 0; j < 8; ++j) acc[i][j] = 0.f;

#pragma unroll 8
    for (int k = 0; k < DIM; ++k) {
        const int m = (k >> 2) & 3;
        const float4 a0 = *(const float4*)&As[k * BM + 8 * (ty ^ m)];
        const float4 a1 = *(const float4*)&As[k * BM + 8 * (ty ^ m) + 4];
        const float4 b0 = *(const float4*)&Bs[k * BM + 8 * (tx ^ m)];
        const float4 b1 = *(const float4*)&Bs[k * BM + 8 * (tx ^ m) + 4];
        const float av[8] = {a0.x, a0.y, a0.z, a0.w, a1.x, a1.y, a1.z, a1.w};
        const float bv[8] = {b0.x, b0.y, b0.z, b0.w, b1.x, b1.y, b1.z, b1.w};
#pragma unroll
        for (int i = 0; i < 8; ++i)
#pragma unroll
            for (int j = 0; j < 8; ++j)
                acc[i][j] = fmaf(av[i], bv[j], acc[i][j]);
    }

    // ---- block-local weighted max ----
    const int row0 = ti * BM + ty * 8;
    const int col0 = tj * BM + tx * 8;
    float lm = -INFINITY;
    if (ti != tj) {
#pragma unroll
        for (int i = 0; i < 8; ++i)
#pragma unroll
            for (int j = 0; j < 8; ++j) lm = fmaxf(lm, acc[i][j]);
    } else {
#pragma unroll
        for (int i = 0; i < 8; ++i)
#pragma unroll
            for (int j = 0; j < 8; ++j)
                if (row0 + i <= col0 + j) lm = fmaxf(lm, acc[i][j]);
    }
    lm *= KAPPA;  // kappa > 0, commutes with max

    __syncthreads();           // all LDS compute reads done
    float* red = As;           // reuse As as reduction scratch
    red[tid] = lm;
    __syncthreads();
#pragma unroll
    for (int s = 128; s > 0; s >>= 1) {
        if (tid < s) red[tid] = fmaxf(red[tid], red[tid + s]);
        __syncthreads();
    }
    const float M = red[0];
    __syncthreads();

    // ---- weighted sum of exp(v - M) ----
    float ls = 0.f;
    if (ti != tj) {
#pragma unroll
        for (int i = 0; i < 8; ++i)
#pragma unroll
            for (int j = 0; j < 8; ++j)
                ls += __expf(KAPPA * acc[i][j] - M);
        ls *= 2.f;  // off-diagonal tile: every entry mirrored
    } else {
#pragma unroll
        for (int i = 0; i < 8; ++i)
#pragma unroll
            for (int j = 0; j < 8; ++j) {
                const int r = row0 + i, c2 = col0 + j;
                if (r <= c2)
                    ls += (r == c2 ? 1.f : 2.f) * __expf(KAPPA * acc[i][j] - M);
            }
    }
    red[tid] = ls;
    __syncthreads();
#pragma unroll
    for (int s = 128; s > 0; s >>= 1) {
        if (tid < s) red[tid] += red[tid + s];
        __syncthreads();
    }
    if (tid == 0) {
        ws[2 * (size_t)bb]     = M;
        ws[2 * (size_t)bb + 1] = red[0];
    }
}

// 1 block, 8 waves: wave w merges batch w's 528 (M,S) pairs, thread 0 averages.
__global__ __launch_bounds__(512)
void reduce_lse(const float* __restrict__ ws, float* __restrict__ out) {
    const int tid  = threadIdx.x;
    const int w    = tid >> 6;
    const int lane = tid & 63;
    __shared__ float lse[BATCH];

    const float* p = ws + (size_t)w * TPB * 2;
    float mv[9], lv[9];
    int cnt = 0;
    for (int idx = lane; idx < TPB; idx += 64) {
        mv[cnt] = p[2 * idx];
        lv[cnt] = p[2 * idx + 1];
        ++cnt;
    }
    float lm = -INFINITY;
    for (int c = 0; c < cnt; ++c) lm = fmaxf(lm, mv[c]);
#pragma unroll
    for (int off = 32; off > 0; off >>= 1) lm = fmaxf(lm, __shfl_down(lm, off));
    const float L = __shfl(lm, 0);

    float s = 0.f;
    for (int c = 0; c < cnt; ++c) s += lv[c] * __expf(mv[c] - L);
#pragma unroll
    for (int off = 32; off > 0; off >>= 1) s += __shfl_down(s, off);

    if (lane == 0) lse[w] = L + logf(s);
    __syncthreads();
    if (tid == 0) {
        float a = 0.f;
        for (int i = 0; i < BATCH; ++i) a += lse[i];
        out[0] = a * (1.f / BATCH);
    }
}

extern "C" void kernel_launch(void* const* d_in, const int* in_sizes, int n_in,
                              void* d_out, int out_size, void* d_ws, size_t ws_size,
                              hipStream_t stream) {
    const float* emb = (const float*)d_in[0];
    float* out = (float*)d_out;
    float* ws  = (float*)d_ws;   // needs BATCH*TPB*2 floats = 33,792 B

    gram_lse_partial<<<BATCH * TPB, 256, 0, stream>>>(emb, ws);
    reduce_lse<<<1, 512, 0, stream>>>(ws, out);
}

// Round 2
// 82.586 us; speedup vs baseline: 2.1090x; 2.1090x over previous
//
#include <hip/hip_runtime.h>
#include <math.h>

#define BATCH 8
#define NTOK  4096
#define DIM   64
#define BM    128
#define NT    (NTOK / BM)            // 32 tiles per dim
#define TPB   (NT * (NT + 1) / 2)    // 528 upper-tri tile pairs per batch
#define KAPPA 0.5f

typedef _Float16 f16x8 __attribute__((ext_vector_type(8)));
typedef float    f32x16 __attribute__((ext_vector_type(16)));

// One block per (batch, upper-tri 128x128 tile pair). Gram tile via
// mfma_f32_32x32x16_f16 (fp32 inputs converted to f16 during LDS staging),
// then block-local (max, sum-exp). Whole-tile weighting (diag=1, offdiag=2)
// makes the epilogue permutation-invariant — no per-element masking.
__global__ __launch_bounds__(256, 2)
void gram_lse_partial(const float* __restrict__ emb, float* __restrict__ ws) {
    // Panels as 16-B units: unit (g, row) at [g*128 + (row^g)], g=k/8 in 0..7.
    // XOR swizzle: staging writes (fixed row, g varies) and fragment reads
    // (fixed g, rows vary) are both bank-conflict-free.
    __shared__ f16x8 As[8 * BM];   // 16 KB
    __shared__ f16x8 Bs[8 * BM];   // 16 KB
    __shared__ float red_m[4], red_s[4];

    const int tid = threadIdx.x;
    const int bb  = blockIdx.x;
    const int b   = bb / TPB;
    int t = bb - b * TPB;
    int ti = 0;
    while (t >= NT - ti) { t -= NT - ti; ++ti; }
    const int tj = ti + t;

    const float* embA = emb + ((size_t)b * NTOK + (size_t)ti * BM) * DIM;
    const float* embB = emb + ((size_t)b * NTOK + (size_t)tj * BM) * DIM;

    // ---- global fp32 -> LDS f16 staging ----
    {
        const int g  = tid & 7;     // k-group: k = 8g..8g+7
        const int r0 = tid >> 3;    // 0..31
#pragma unroll
        for (int p = 0; p < 4; ++p) {
            const int row = r0 + 32 * p;
            const float4 a0 = *(const float4*)(embA + (size_t)row * DIM + g * 8);
            const float4 a1 = *(const float4*)(embA + (size_t)row * DIM + g * 8 + 4);
            const float4 b0 = *(const float4*)(embB + (size_t)row * DIM + g * 8);
            const float4 b1 = *(const float4*)(embB + (size_t)row * DIM + g * 8 + 4);
            f16x8 pa, pb;
            pa[0] = (_Float16)a0.x; pa[1] = (_Float16)a0.y;
            pa[2] = (_Float16)a0.z; pa[3] = (_Float16)a0.w;
            pa[4] = (_Float16)a1.x; pa[5] = (_Float16)a1.y;
            pa[6] = (_Float16)a1.z; pa[7] = (_Float16)a1.w;
            pb[0] = (_Float16)b0.x; pb[1] = (_Float16)b0.y;
            pb[2] = (_Float16)b0.z; pb[3] = (_Float16)b0.w;
            pb[4] = (_Float16)b1.x; pb[5] = (_Float16)b1.y;
            pb[6] = (_Float16)b1.z; pb[7] = (_Float16)b1.w;
            As[g * BM + (row ^ g)] = pa;
            Bs[g * BM + (row ^ g)] = pb;
        }
    }
    __syncthreads();

    // ---- MFMA: each wave computes a 64x64 subtile (2x2 of 32x32, K=64) ----
    const int lane = tid & 63;
    const int w    = tid >> 6;
    const int half = lane >> 5;    // k-half within fragment
    const int ln31 = lane & 31;
    const int waveR = (w & 1) * 64;
    const int waveC = (w >> 1) * 64;

    f32x16 acc00 = {}, acc01 = {}, acc10 = {}, acc11 = {};
#pragma unroll
    for (int s = 0; s < 4; ++s) {
        const int g = 2 * s + half;
        const f16x8 a0 = As[g * BM + ((waveR + ln31) ^ g)];
        const f16x8 a1 = As[g * BM + ((waveR + 32 + ln31) ^ g)];
        const f16x8 b0 = Bs[g * BM + ((waveC + ln31) ^ g)];
        const f16x8 b1 = Bs[g * BM + ((waveC + 32 + ln31) ^ g)];
        acc00 = __builtin_amdgcn_mfma_f32_32x32x16_f16(a0, b0, acc00, 0, 0, 0);
        acc01 = __builtin_amdgcn_mfma_f32_32x32x16_f16(a0, b1, acc01, 0, 0, 0);
        acc10 = __builtin_amdgcn_mfma_f32_32x32x16_f16(a1, b0, acc10, 0, 0, 0);
        acc11 = __builtin_amdgcn_mfma_f32_32x32x16_f16(a1, b1, acc11, 0, 0, 0);
    }

    // ---- epilogue: block (max, sum-exp); permutation-invariant ----
    float lm = -INFINITY;
#pragma unroll
    for (int e = 0; e < 16; ++e) {
        lm = fmaxf(lm, acc00[e]); lm = fmaxf(lm, acc01[e]);
        lm = fmaxf(lm, acc10[e]); lm = fmaxf(lm, acc11[e]);
    }
#pragma unroll
    for (int off = 32; off > 0; off >>= 1)
        lm = fmaxf(lm, __shfl_xor(lm, off));
    if (lane == 0) red_m[w] = lm;
    __syncthreads();
    const float M = KAPPA * fmaxf(fmaxf(red_m[0], red_m[1]),
                                  fmaxf(red_m[2], red_m[3]));

    float lsum = 0.f;
#pragma unroll
    for (int e = 0; e < 16; ++e) {
        lsum += __expf(fmaf(KAPPA, acc00[e], -M));
        lsum += __expf(fmaf(KAPPA, acc01[e], -M));
        lsum += __expf(fmaf(KAPPA, acc10[e], -M));
        lsum += __expf(fmaf(KAPPA, acc11[e], -M));
    }
#pragma unroll
    for (int off = 32; off > 0; off >>= 1)
        lsum += __shfl_xor(lsum, off);
    if (lane == 0) red_s[w] = lsum;
    __syncthreads();
    if (tid == 0) {
        const float wgt = (ti == tj) ? 1.f : 2.f;
        ws[2 * (size_t)bb]     = M;
        ws[2 * (size_t)bb + 1] = wgt * (red_s[0] + red_s[1] + red_s[2] + red_s[3]);
    }
}

// 1 block, 8 waves: wave w merges batch w's 528 (M,S) pairs, thread 0 averages.
__global__ __launch_bounds__(512)
void reduce_lse(const float* __restrict__ ws, float* __restrict__ out) {
    const int tid  = threadIdx.x;
    const int w    = tid >> 6;
    const int lane = tid & 63;
    __shared__ float lse[BATCH];

    const float* p = ws + (size_t)w * TPB * 2;
    float mv[9], lv[9];
    int cnt = 0;
    for (int idx = lane; idx < TPB; idx += 64) {
        mv[cnt] = p[2 * idx];
        lv[cnt] = p[2 * idx + 1];
        ++cnt;
    }
    float lm = -INFINITY;
    for (int c = 0; c < cnt; ++c) lm = fmaxf(lm, mv[c]);
#pragma unroll
    for (int off = 32; off > 0; off >>= 1) lm = fmaxf(lm, __shfl_down(lm, off));
    const float L = __shfl(lm, 0);

    float s = 0.f;
    for (int c = 0; c < cnt; ++c) s += lv[c] * __expf(mv[c] - L);
#pragma unroll
    for (int off = 32; off > 0; off >>= 1) s += __shfl_down(s, off);

    if (lane == 0) lse[w] = L + logf(s);
    __syncthreads();
    if (tid == 0) {
        float a = 0.f;
        for (int i = 0; i < BATCH; ++i) a += lse[i];
        out[0] = a * (1.f / BATCH);
    }
}

extern "C" void kernel_launch(void* const* d_in, const int* in_sizes, int n_in,
                              void* d_out, int out_size, void* d_ws, size_t ws_size,
                              hipStream_t stream) {
    const float* emb = (const float*)d_in[0];
    float* out = (float*)d_out;
    float* ws  = (float*)d_ws;   // BATCH*TPB*2 floats = 33,792 B

    gram_lse_partial<<<BATCH * TPB, 256, 0, stream>>>(emb, ws);
    reduce_lse<<<1, 512, 0, stream>>>(ws, out);
}